// Round 1
// baseline (5612.829 us; speedup 1.0000x reference)
//
#include <hip/hip_runtime.h>

#define D 128
#define TILE_R 32
#define LDS_STRIDE 260   // 256 + 4 pad: conflict-free b128 reads, keeps 16B alignment

// ---- scatter: agg[dst] += feat[src], one edge per 32-lane group, float4/lane ----
__global__ __launch_bounds__(256) void scatter_add_kernel(
    const float* __restrict__ feat, const int* __restrict__ src,
    const int* __restrict__ dst, float* agg, int nedges)
{
    int tid = blockIdx.x * 256 + threadIdx.x;
    int e = tid >> 5;
    if (e >= nedges) return;
    int l = tid & 31;
    int s = src[e];
    int d = dst[e];
    const float4 v = *reinterpret_cast<const float4*>(feat + (size_t)s * D + l * 4);
    float* o = agg + (size_t)d * D + l * 4;
    unsafeAtomicAdd(o + 0, v.x);
    unsafeAtomicAdd(o + 1, v.y);
    unsafeAtomicAdd(o + 2, v.z);
    unsafeAtomicAdd(o + 3, v.w);
}

// ---- fused GEMM: out = maybe_relu([A1|A2] @ [Wrel;Wroot] + bias) ----
// 256 threads/block, 32 rows/block, each thread 4 rows x 4 cols.
// NOTE: A2 and out may alias (in-place layer): each block stages its own 32 rows
// into LDS (barrier) before writing them; blocks touch disjoint rows -> safe.
__global__ __launch_bounds__(256) void gemm_fused_kernel(
    const float* __restrict__ A1,    // agg  [n,128]
    const float* A2,                 // x/h  [n,128]  (may alias out)
    const float* __restrict__ Wrel,  // [128,128]
    const float* __restrict__ Wroot, // [128,128]
    const float* __restrict__ bias,  // [128]
    float* out,                      // [n,128]
    int n, int do_relu)
{
    __shared__ float As[TILE_R * LDS_STRIDE];
    const int t = threadIdx.x;
    const int base = blockIdx.x * TILE_R;

    // stage 32 rows x 256 K  (cols 0..127 from A1, 128..255 from A2)
    #pragma unroll
    for (int m = 0; m < 8; ++m) {
        int q = t + m * 256;          // 0..2047
        int r = q >> 6;               // row in tile
        int kk = (q & 63) << 2;       // k (float4 granular)
        int row = base + r;
        float4 v = make_float4(0.f, 0.f, 0.f, 0.f);
        if (row < n) {
            const float* p = (kk < 128) ? (A1 + (size_t)row * D + kk)
                                        : (A2 + (size_t)row * D + (kk - 128));
            v = *reinterpret_cast<const float4*>(p);
        }
        *reinterpret_cast<float4*>(&As[r * LDS_STRIDE + kk]) = v;
    }
    __syncthreads();

    const int rg = t >> 5;            // row group 0..7
    const int c0 = (t & 31) << 2;     // col 0..124

    float acc[4][4];
    #pragma unroll
    for (int i = 0; i < 4; ++i)
        #pragma unroll
        for (int j = 0; j < 4; ++j) acc[i][j] = 0.f;

    const float* Wmats[2] = {Wrel, Wroot};
    #pragma unroll
    for (int half = 0; half < 2; ++half) {
        const float* W = Wmats[half];
        const int kb = half * 128;
        for (int k = 0; k < 128; k += 4) {
            float w[4][4];
            #pragma unroll
            for (int kk = 0; kk < 4; ++kk) {
                float4 wv = *reinterpret_cast<const float4*>(W + (size_t)(k + kk) * D + c0);
                w[kk][0] = wv.x; w[kk][1] = wv.y; w[kk][2] = wv.z; w[kk][3] = wv.w;
            }
            #pragma unroll
            for (int i = 0; i < 4; ++i) {
                float4 av = *reinterpret_cast<const float4*>(&As[(rg * 4 + i) * LDS_STRIDE + kb + k]);
                float a[4] = {av.x, av.y, av.z, av.w};
                #pragma unroll
                for (int kk = 0; kk < 4; ++kk)
                    #pragma unroll
                    for (int j = 0; j < 4; ++j)
                        acc[i][j] = fmaf(a[kk], w[kk][j], acc[i][j]);
            }
        }
    }

    float4 bv = *reinterpret_cast<const float4*>(bias + c0);
    float b[4] = {bv.x, bv.y, bv.z, bv.w};
    #pragma unroll
    for (int i = 0; i < 4; ++i) {
        int row = base + rg * 4 + i;
        if (row >= n) continue;
        float o[4];
        #pragma unroll
        for (int j = 0; j < 4; ++j) {
            float v = acc[i][j] + b[j];
            if (do_relu) v = fmaxf(v, 0.f);
            o[j] = v;
        }
        *reinterpret_cast<float4*>(out + (size_t)row * D + c0) =
            make_float4(o[0], o[1], o[2], o[3]);
    }
}

extern "C" void kernel_launch(void* const* d_in, const int* in_sizes, int n_in,
                              void* d_out, int out_size, void* d_ws, size_t ws_size,
                              hipStream_t stream) {
    const float* x       = (const float*)d_in[0];
    const int*   ei      = (const int*)d_in[1];   // [2,E] int32 (harness converts int64->int32)
    const float* W1_rel  = (const float*)d_in[2];
    const float* b1      = (const float*)d_in[3];
    const float* W1_root = (const float*)d_in[4];
    const float* W2_rel  = (const float*)d_in[5];
    const float* b2      = (const float*)d_in[6];
    const float* W2_root = (const float*)d_in[7];
    float* out = (float*)d_out;

    const int E = in_sizes[1] / 2;
    const int N = in_sizes[0] / D;
    const int* src = ei;
    const int* dst = ei + E;

    float* agg = (float*)d_ws;            // [N,128]
    float* h   = out;                     // layer-1 activations live in d_out
    size_t aggBytes = (size_t)N * D * sizeof(float);

    int scatterBlocks = (E * 32 + 255) / 256;
    int gemmBlocks = (N + TILE_R - 1) / TILE_R;

    // layer 1
    hipMemsetAsync(agg, 0, aggBytes, stream);
    scatter_add_kernel<<<scatterBlocks, 256, 0, stream>>>(x, src, dst, agg, E);
    gemm_fused_kernel<<<gemmBlocks, 256, 0, stream>>>(agg, x, W1_rel, W1_root, b1, h, N, 1);

    // layer 2 (h read in-place from d_out, out written in-place)
    hipMemsetAsync(agg, 0, aggBytes, stream);
    scatter_add_kernel<<<scatterBlocks, 256, 0, stream>>>(h, src, dst, agg, E);
    gemm_fused_kernel<<<gemmBlocks, 256, 0, stream>>>(agg, h, W2_rel, W2_root, b2, out, N, 0);
}

// Round 2
// 666.862 us; speedup vs baseline: 8.4168x; 8.4168x over previous
//
#include <hip/hip_runtime.h>

#define D 128
#define TILE_R 32
#define LDS_STRIDE 260   // 256 + 4 pad: conflict-free b128 reads, keeps 16B alignment
#define SCAN_CHUNK 2048  // 256 threads x 8 elements

// ================= CSR build =================

__global__ __launch_bounds__(256) void hist_kernel(
    const int* __restrict__ dst, int* __restrict__ cnt, int nedges)
{
    int e = blockIdx.x * 256 + threadIdx.x;
    if (e < nedges) atomicAdd(&cnt[dst[e]], 1);
}

// pass A: per-chunk sums
__global__ __launch_bounds__(256) void scan_reduce_kernel(
    const int* __restrict__ cnt, int* __restrict__ partials, int n)
{
    __shared__ int sh[256];
    int b = blockIdx.x, t = threadIdx.x;
    int base = b * SCAN_CHUNK;
    int sum = 0;
    #pragma unroll
    for (int i = 0; i < 8; ++i) {
        int idx = base + i * 256 + t;
        if (idx < n) sum += cnt[idx];
    }
    sh[t] = sum; __syncthreads();
    for (int off = 128; off > 0; off >>= 1) {
        if (t < off) sh[t] += sh[t + off];
        __syncthreads();
    }
    if (t == 0) partials[b] = sh[0];
}

// pass B: serial exclusive scan of chunk partials (small: ~49)
__global__ void scan_partials_kernel(int* partials, int nchunks)
{
    if (threadIdx.x == 0 && blockIdx.x == 0) {
        int run = 0;
        for (int i = 0; i < nchunks; ++i) {
            int v = partials[i];
            partials[i] = run;
            run += v;
        }
    }
}

// pass C: in-place exclusive scan of each chunk (+ chunk offset)
__global__ __launch_bounds__(256) void scan_final_kernel(
    int* __restrict__ ptr, const int* __restrict__ partials, int n)
{
    __shared__ int sh[256];
    int b = blockIdx.x, t = threadIdx.x;
    int base = b * SCAN_CHUNK;

    int v[8];
    int ts = 0;
    #pragma unroll
    for (int i = 0; i < 8; ++i) {
        int idx = base + t * 8 + i;
        v[i] = (idx < n) ? ptr[idx] : 0;
        ts += v[i];
    }
    // Hillis-Steele inclusive scan of thread sums
    int val = ts;
    sh[t] = val; __syncthreads();
    for (int off = 1; off < 256; off <<= 1) {
        int u = (t >= off) ? sh[t - off] : 0;
        __syncthreads();
        val += u;
        sh[t] = val;
        __syncthreads();
    }
    int run = partials[b] + (val - ts);   // exclusive offset for this thread
    #pragma unroll
    for (int i = 0; i < 8; ++i) {
        int idx = base + t * 8 + i;
        if (idx < n) ptr[idx] = run;
        run += v[i];
    }
}

// fill: pos = ptr[dst]++ ; after this, ptr[i] == end_i (start_i = i? ptr[i-1] : 0)
__global__ __launch_bounds__(256) void fill_kernel(
    const int* __restrict__ src, const int* __restrict__ dst,
    int* __restrict__ ptr, int* __restrict__ csr_src, int nedges)
{
    int e = blockIdx.x * 256 + threadIdx.x;
    if (e < nedges) {
        int pos = atomicAdd(&ptr[dst[e]], 1);
        csr_src[pos] = src[e];
    }
}

// ================= aggregation: agg[i] = sum over nbrs x[src] =================
// 32-lane group per node (float4/lane covers the 128-f32 row), 8 nodes/block.
__global__ __launch_bounds__(256) void gather_sum_kernel(
    const float* __restrict__ feat, const int* __restrict__ csr_src,
    const int* __restrict__ ends, float* __restrict__ agg, int n)
{
    int node = blockIdx.x * 8 + (threadIdx.x >> 5);
    if (node >= n) return;
    int l = threadIdx.x & 31;
    int start = (node == 0) ? 0 : ends[node - 1];
    int end = ends[node];
    float4 acc = make_float4(0.f, 0.f, 0.f, 0.f);
    for (int j = start; j < end; ++j) {
        int s = csr_src[j];
        const float4 v = *reinterpret_cast<const float4*>(feat + (size_t)s * D + l * 4);
        acc.x += v.x; acc.y += v.y; acc.z += v.z; acc.w += v.w;
    }
    *reinterpret_cast<float4*>(agg + (size_t)node * D + l * 4) = acc;
}

// ================= fallback scatter (only if ws too small) =================
__global__ __launch_bounds__(256) void scatter_add_kernel(
    const float* __restrict__ feat, const int* __restrict__ src,
    const int* __restrict__ dst, float* agg, int nedges)
{
    int tid = blockIdx.x * 256 + threadIdx.x;
    int e = tid >> 5;
    if (e >= nedges) return;
    int l = tid & 31;
    int s = src[e];
    int d = dst[e];
    const float4 v = *reinterpret_cast<const float4*>(feat + (size_t)s * D + l * 4);
    float* o = agg + (size_t)d * D + l * 4;
    unsafeAtomicAdd(o + 0, v.x);
    unsafeAtomicAdd(o + 1, v.y);
    unsafeAtomicAdd(o + 2, v.z);
    unsafeAtomicAdd(o + 3, v.w);
}

// ================= fused GEMM: out = maybe_relu([A1|A2] @ [Wrel;Wroot] + bias) =================
__global__ __launch_bounds__(256) void gemm_fused_kernel(
    const float* __restrict__ A1,    // agg  [n,128]
    const float* A2,                 // x/h  [n,128]  (may alias out)
    const float* __restrict__ Wrel,  // [128,128]
    const float* __restrict__ Wroot, // [128,128]
    const float* __restrict__ bias,  // [128]
    float* out,                      // [n,128]
    int n, int do_relu)
{
    __shared__ float As[TILE_R * LDS_STRIDE];
    const int t = threadIdx.x;
    const int base = blockIdx.x * TILE_R;

    #pragma unroll
    for (int m = 0; m < 8; ++m) {
        int q = t + m * 256;
        int r = q >> 6;
        int kk = (q & 63) << 2;
        int row = base + r;
        float4 v = make_float4(0.f, 0.f, 0.f, 0.f);
        if (row < n) {
            const float* p = (kk < 128) ? (A1 + (size_t)row * D + kk)
                                        : (A2 + (size_t)row * D + (kk - 128));
            v = *reinterpret_cast<const float4*>(p);
        }
        *reinterpret_cast<float4*>(&As[r * LDS_STRIDE + kk]) = v;
    }
    __syncthreads();

    const int rg = t >> 5;
    const int c0 = (t & 31) << 2;

    float acc[4][4];
    #pragma unroll
    for (int i = 0; i < 4; ++i)
        #pragma unroll
        for (int j = 0; j < 4; ++j) acc[i][j] = 0.f;

    const float* Wmats[2] = {Wrel, Wroot};
    #pragma unroll
    for (int half = 0; half < 2; ++half) {
        const float* W = Wmats[half];
        const int kb = half * 128;
        for (int k = 0; k < 128; k += 4) {
            float w[4][4];
            #pragma unroll
            for (int kk = 0; kk < 4; ++kk) {
                float4 wv = *reinterpret_cast<const float4*>(W + (size_t)(k + kk) * D + c0);
                w[kk][0] = wv.x; w[kk][1] = wv.y; w[kk][2] = wv.z; w[kk][3] = wv.w;
            }
            #pragma unroll
            for (int i = 0; i < 4; ++i) {
                float4 av = *reinterpret_cast<const float4*>(&As[(rg * 4 + i) * LDS_STRIDE + kb + k]);
                float a[4] = {av.x, av.y, av.z, av.w};
                #pragma unroll
                for (int kk = 0; kk < 4; ++kk)
                    #pragma unroll
                    for (int j = 0; j < 4; ++j)
                        acc[i][j] = fmaf(a[kk], w[kk][j], acc[i][j]);
            }
        }
    }

    float4 bv = *reinterpret_cast<const float4*>(bias + c0);
    float b[4] = {bv.x, bv.y, bv.z, bv.w};
    #pragma unroll
    for (int i = 0; i < 4; ++i) {
        int row = base + rg * 4 + i;
        if (row >= n) continue;
        float o[4];
        #pragma unroll
        for (int j = 0; j < 4; ++j) {
            float v = acc[i][j] + b[j];
            if (do_relu) v = fmaxf(v, 0.f);
            o[j] = v;
        }
        *reinterpret_cast<float4*>(out + (size_t)row * D + c0) =
            make_float4(o[0], o[1], o[2], o[3]);
    }
}

extern "C" void kernel_launch(void* const* d_in, const int* in_sizes, int n_in,
                              void* d_out, int out_size, void* d_ws, size_t ws_size,
                              hipStream_t stream) {
    const float* x       = (const float*)d_in[0];
    const int*   ei      = (const int*)d_in[1];
    const float* W1_rel  = (const float*)d_in[2];
    const float* b1      = (const float*)d_in[3];
    const float* W1_root = (const float*)d_in[4];
    const float* W2_rel  = (const float*)d_in[5];
    const float* b2      = (const float*)d_in[6];
    const float* W2_root = (const float*)d_in[7];
    float* out = (float*)d_out;

    const int E = in_sizes[1] / 2;
    const int N = in_sizes[0] / D;
    const int* src = ei;
    const int* dst = ei + E;

    size_t aggBytes = (size_t)N * D * sizeof(float);
    size_t csrBytes = (size_t)E * sizeof(int);
    size_t ptrBytes = (size_t)(N + 1) * sizeof(int);
    int nchunks = (N + SCAN_CHUNK - 1) / SCAN_CHUNK;
    size_t partBytes = (size_t)(nchunks + 1) * sizeof(int);
    size_t need = aggBytes + csrBytes + ptrBytes + partBytes;

    int gemmBlocks = (N + TILE_R - 1) / TILE_R;
    int eBlocks = (E + 255) / 256;

    if (ws_size >= need) {
        // ---- CSR path ----
        float* agg     = (float*)d_ws;
        int*   csr_src = (int*)((char*)d_ws + aggBytes);
        int*   ptr     = csr_src + E;
        int*   partials= ptr + (N + 1);

        hipMemsetAsync(ptr, 0, ptrBytes, stream);
        hist_kernel<<<eBlocks, 256, 0, stream>>>(dst, ptr, E);
        scan_reduce_kernel<<<nchunks, 256, 0, stream>>>(ptr, partials, N);
        scan_partials_kernel<<<1, 64, 0, stream>>>(partials, nchunks);
        scan_final_kernel<<<nchunks, 256, 0, stream>>>(ptr, partials, N);
        fill_kernel<<<eBlocks, 256, 0, stream>>>(src, dst, ptr, csr_src, E);
        // ptr now holds ends: start_i = (i==0)?0:ptr[i-1]

        int gatherBlocks = (N + 7) / 8;
        // layer 1
        gather_sum_kernel<<<gatherBlocks, 256, 0, stream>>>(x, csr_src, ptr, agg, N);
        gemm_fused_kernel<<<gemmBlocks, 256, 0, stream>>>(agg, x, W1_rel, W1_root, b1, out, N, 1);
        // layer 2 (h lives in d_out; gather completes before in-place gemm)
        gather_sum_kernel<<<gatherBlocks, 256, 0, stream>>>(out, csr_src, ptr, agg, N);
        gemm_fused_kernel<<<gemmBlocks, 256, 0, stream>>>(agg, out, W2_rel, W2_root, b2, out, N, 0);
    } else {
        // ---- fallback: atomic scatter path ----
        float* agg = (float*)d_ws;
        int scatterBlocks = (E * 32 + 255) / 256;
        hipMemsetAsync(agg, 0, aggBytes, stream);
        scatter_add_kernel<<<scatterBlocks, 256, 0, stream>>>(x, src, dst, agg, E);
        gemm_fused_kernel<<<gemmBlocks, 256, 0, stream>>>(agg, x, W1_rel, W1_root, b1, out, N, 1);
        hipMemsetAsync(agg, 0, aggBytes, stream);
        scatter_add_kernel<<<scatterBlocks, 256, 0, stream>>>(out, src, dst, agg, E);
        gemm_fused_kernel<<<gemmBlocks, 256, 0, stream>>>(agg, out, W2_rel, W2_root, b2, out, N, 0);
    }
}

// Round 3
// 431.589 us; speedup vs baseline: 13.0050x; 1.5451x over previous
//
#include <hip/hip_runtime.h>

#define D 128
#define SCAN_CHUNK 2048
#define LDS_STRIDE 260    // fp32 fallback gemm
#define TILE_R 32
#define GBM 64            // mfma gemm rows/block
#define APAD 264          // 256 bf16 + 8 pad -> 528B row stride (2-way bank alias, free)

typedef __attribute__((ext_vector_type(8))) short bf16x8;
typedef __attribute__((ext_vector_type(4))) float f32x4;

static __device__ __forceinline__ ushort f2b(float f) {
    union { float f; uint u; } v; v.f = f;
    uint r = (v.u + 0x7FFFu + ((v.u >> 16) & 1u)) >> 16;   // RNE
    return (ushort)r;
}
static __device__ __forceinline__ float blo(uint u) {
    union { uint u; float f; } v; v.u = u << 16; return v.f;
}
static __device__ __forceinline__ float bhi(uint u) {
    union { uint u; float f; } v; v.u = u & 0xFFFF0000u; return v.f;
}

// ================= CSR build =================

__global__ __launch_bounds__(256) void hist_kernel(
    const int* __restrict__ dst, int* __restrict__ cnt, int nedges)
{
    int e = blockIdx.x * 256 + threadIdx.x;
    if (e < nedges) atomicAdd(&cnt[dst[e]], 1);
}

__global__ __launch_bounds__(256) void scan_reduce_kernel(
    const int* __restrict__ cnt, int* __restrict__ partials, int n)
{
    __shared__ int sh[256];
    int b = blockIdx.x, t = threadIdx.x;
    int base = b * SCAN_CHUNK;
    int sum = 0;
    #pragma unroll
    for (int i = 0; i < 8; ++i) {
        int idx = base + i * 256 + t;
        if (idx < n) sum += cnt[idx];
    }
    sh[t] = sum; __syncthreads();
    for (int off = 128; off > 0; off >>= 1) {
        if (t < off) sh[t] += sh[t + off];
        __syncthreads();
    }
    if (t == 0) partials[b] = sh[0];
}

__global__ void scan_partials_kernel(int* partials, int nchunks)
{
    if (threadIdx.x == 0 && blockIdx.x == 0) {
        int run = 0;
        for (int i = 0; i < nchunks; ++i) {
            int v = partials[i];
            partials[i] = run;
            run += v;
        }
    }
}

__global__ __launch_bounds__(256) void scan_final_kernel(
    int* __restrict__ ptr, const int* __restrict__ partials, int n)
{
    __shared__ int sh[256];
    int b = blockIdx.x, t = threadIdx.x;
    int base = b * SCAN_CHUNK;

    int v[8];
    int ts = 0;
    #pragma unroll
    for (int i = 0; i < 8; ++i) {
        int idx = base + t * 8 + i;
        v[i] = (idx < n) ? ptr[idx] : 0;
        ts += v[i];
    }
    int val = ts;
    sh[t] = val; __syncthreads();
    for (int off = 1; off < 256; off <<= 1) {
        int u = (t >= off) ? sh[t - off] : 0;
        __syncthreads();
        val += u;
        sh[t] = val;
        __syncthreads();
    }
    int run = partials[b] + (val - ts);
    #pragma unroll
    for (int i = 0; i < 8; ++i) {
        int idx = base + t * 8 + i;
        if (idx < n) ptr[idx] = run;
        run += v[i];
    }
}

__global__ __launch_bounds__(256) void fill_kernel(
    const int* __restrict__ src, const int* __restrict__ dst,
    int* __restrict__ ptr, int* __restrict__ csr_src, int nedges)
{
    int e = blockIdx.x * 256 + threadIdx.x;
    if (e < nedges) {
        int pos = atomicAdd(&ptr[dst[e]], 1);
        csr_src[pos] = src[e];
    }
}

// ================= converts =================

// 8 f32 -> 8 bf16 per thread
__global__ __launch_bounds__(256) void conv_f32_bf16_kernel(
    const float* __restrict__ in, ushort* __restrict__ out, int n8)
{
    int i = blockIdx.x * 256 + threadIdx.x;
    if (i >= n8) return;
    float4 a = reinterpret_cast<const float4*>(in)[i * 2];
    float4 b = reinterpret_cast<const float4*>(in)[i * 2 + 1];
    uint4 r;
    r.x = f2b(a.x) | ((uint)f2b(a.y) << 16);
    r.y = f2b(a.z) | ((uint)f2b(a.w) << 16);
    r.z = f2b(b.x) | ((uint)f2b(b.y) << 16);
    r.w = f2b(b.z) | ((uint)f2b(b.w) << 16);
    reinterpret_cast<uint4*>(out)[i] = r;
}

// Wt[n][k] (bf16, [128][256]) = concat(Wrel, Wroot)^T ; idx = n*256+k
__global__ __launch_bounds__(256) void wt_kernel(
    const float* __restrict__ Wrel, const float* __restrict__ Wroot,
    ushort* __restrict__ Wt)
{
    int idx = blockIdx.x * 256 + threadIdx.x;   // 128*256 total
    int n = idx >> 8, k = idx & 255;
    float v = (k < 128) ? Wrel[(size_t)k * D + n] : Wroot[(size_t)(k - 128) * D + n];
    Wt[idx] = f2b(v);
}

// ================= gather-sum (bf16 in, bf16 out) =================
// 16 lanes/node, 16B (8 bf16) per lane; fp32 accumulate.
__global__ __launch_bounds__(256) void gather_sum_bf16_kernel(
    const ushort* __restrict__ feat, const int* __restrict__ csr_src,
    const int* __restrict__ ends, ushort* __restrict__ aggb, int n)
{
    int node = blockIdx.x * 16 + (threadIdx.x >> 4);
    if (node >= n) return;
    int l = threadIdx.x & 15;
    int start = (node == 0) ? 0 : ends[node - 1];
    int end = ends[node];
    float a0=0,a1=0,a2=0,a3=0,a4=0,a5=0,a6=0,a7=0;
    for (int j = start; j < end; ++j) {
        int s = csr_src[j];
        uint4 v = reinterpret_cast<const uint4*>(feat + (size_t)s * D)[l];
        a0 += blo(v.x); a1 += bhi(v.x);
        a2 += blo(v.y); a3 += bhi(v.y);
        a4 += blo(v.z); a5 += bhi(v.z);
        a6 += blo(v.w); a7 += bhi(v.w);
    }
    uint4 r;
    r.x = f2b(a0) | ((uint)f2b(a1) << 16);
    r.y = f2b(a2) | ((uint)f2b(a3) << 16);
    r.z = f2b(a4) | ((uint)f2b(a5) << 16);
    r.w = f2b(a6) | ((uint)f2b(a7) << 16);
    reinterpret_cast<uint4*>(aggb + (size_t)node * D)[l] = r;
}

// ================= MFMA GEMM =================
// out = maybe_relu([A1|A2](bf16, K=256) @ Wt^T + bias)
// 256 thr = 4 waves; block = 64 rows x 128 cols; wave = 64 rows x 32 cols.
// mode 0: write bf16 to outb (relu);  mode 1: write f32 to outf (no relu).
// A2 may alias outb: block stages its own rows to LDS before the barrier,
// writes only those rows after -> safe.
__global__ __launch_bounds__(256) void gemm_mfma_kernel(
    const ushort* __restrict__ A1, const ushort* A2,
    const ushort* __restrict__ Wt, const float* __restrict__ bias,
    float* outf, ushort* outb, int n, int mode)
{
    __shared__ ushort As[GBM * APAD];
    const int t = threadIdx.x;
    const int wave = t >> 6, lane = t & 63;
    const int base = blockIdx.x * GBM;

    // stage A tile: 64 rows x 256 bf16 (cols 0..127 from A1, 128..255 from A2)
    #pragma unroll
    for (int m = 0; m < 8; ++m) {
        int q = t + m * 256;          // 0..2047 16B-chunks
        int r = q >> 5;               // row in tile
        int c = q & 31;               // 16B chunk within row
        int row = base + r;
        uint4 v = make_uint4(0, 0, 0, 0);
        if (row < n)
            v = (c < 16) ? reinterpret_cast<const uint4*>(A1 + (size_t)row * D)[c]
                         : reinterpret_cast<const uint4*>(A2 + (size_t)row * D)[c - 16];
        *reinterpret_cast<uint4*>(&As[r * APAD + c * 8]) = v;
    }

    // B fragments in registers: wave's 32 cols x K=256
    const int bcol0 = wave * 32;
    bf16x8 Bfrag[2][8];
    #pragma unroll
    for (int nt = 0; nt < 2; ++nt)
        #pragma unroll
        for (int ks = 0; ks < 8; ++ks) {
            int ncol = bcol0 + nt * 16 + (lane & 15);
            int k = ks * 32 + (lane >> 4) * 8;
            Bfrag[nt][ks] = *reinterpret_cast<const bf16x8*>(Wt + (size_t)ncol * 256 + k);
        }

    __syncthreads();

    f32x4 acc[4][2];
    #pragma unroll
    for (int rt = 0; rt < 4; ++rt)
        #pragma unroll
        for (int nt = 0; nt < 2; ++nt) acc[rt][nt] = (f32x4){0.f, 0.f, 0.f, 0.f};

    #pragma unroll
    for (int ks = 0; ks < 8; ++ks) {
        bf16x8 a[4];
        #pragma unroll
        for (int rt = 0; rt < 4; ++rt) {
            int r = rt * 16 + (lane & 15);
            int k = ks * 32 + (lane >> 4) * 8;
            a[rt] = *reinterpret_cast<const bf16x8*>(&As[r * APAD + k]);
        }
        #pragma unroll
        for (int rt = 0; rt < 4; ++rt)
            #pragma unroll
            for (int nt = 0; nt < 2; ++nt)
                acc[rt][nt] = __builtin_amdgcn_mfma_f32_16x16x32_bf16(
                    a[rt], Bfrag[nt][ks], acc[rt][nt], 0, 0, 0);
    }

    // epilogue: C layout col = lane&15, row = (lane>>4)*4 + reg
    #pragma unroll
    for (int rt = 0; rt < 4; ++rt)
        #pragma unroll
        for (int nt = 0; nt < 2; ++nt) {
            int col = bcol0 + nt * 16 + (lane & 15);
            float bv = bias[col];
            #pragma unroll
            for (int r = 0; r < 4; ++r) {
                int row = base + rt * 16 + (lane >> 4) * 4 + r;
                if (row >= n) continue;
                float v = acc[rt][nt][r] + bv;
                if (mode == 0) {
                    v = fmaxf(v, 0.f);
                    outb[(size_t)row * D + col] = f2b(v);
                } else {
                    outf[(size_t)row * D + col] = v;
                }
            }
        }
}

// ================= fp32 fallback (small ws) =================

__global__ __launch_bounds__(256) void scatter_add_kernel(
    const float* __restrict__ feat, const int* __restrict__ src,
    const int* __restrict__ dst, float* agg, int nedges)
{
    int tid = blockIdx.x * 256 + threadIdx.x;
    int e = tid >> 5;
    if (e >= nedges) return;
    int l = tid & 31;
    int s = src[e];
    int d = dst[e];
    const float4 v = *reinterpret_cast<const float4*>(feat + (size_t)s * D + l * 4);
    float* o = agg + (size_t)d * D + l * 4;
    unsafeAtomicAdd(o + 0, v.x);
    unsafeAtomicAdd(o + 1, v.y);
    unsafeAtomicAdd(o + 2, v.z);
    unsafeAtomicAdd(o + 3, v.w);
}

__global__ __launch_bounds__(256) void gemm_fused_kernel(
    const float* __restrict__ A1, const float* A2,
    const float* __restrict__ Wrel, const float* __restrict__ Wroot,
    const float* __restrict__ bias, float* out, int n, int do_relu)
{
    __shared__ float Asf[TILE_R * LDS_STRIDE];
    const int t = threadIdx.x;
    const int base = blockIdx.x * TILE_R;

    #pragma unroll
    for (int m = 0; m < 8; ++m) {
        int q = t + m * 256;
        int r = q >> 6;
        int kk = (q & 63) << 2;
        int row = base + r;
        float4 v = make_float4(0.f, 0.f, 0.f, 0.f);
        if (row < n) {
            const float* p = (kk < 128) ? (A1 + (size_t)row * D + kk)
                                        : (A2 + (size_t)row * D + (kk - 128));
            v = *reinterpret_cast<const float4*>(p);
        }
        *reinterpret_cast<float4*>(&Asf[r * LDS_STRIDE + kk]) = v;
    }
    __syncthreads();

    const int rg = t >> 5;
    const int c0 = (t & 31) << 2;

    float acc[4][4];
    #pragma unroll
    for (int i = 0; i < 4; ++i)
        #pragma unroll
        for (int j = 0; j < 4; ++j) acc[i][j] = 0.f;

    const float* Wmats[2] = {Wrel, Wroot};
    #pragma unroll
    for (int half = 0; half < 2; ++half) {
        const float* W = Wmats[half];
        const int kb = half * 128;
        for (int k = 0; k < 128; k += 4) {
            float w[4][4];
            #pragma unroll
            for (int kk = 0; kk < 4; ++kk) {
                float4 wv = *reinterpret_cast<const float4*>(W + (size_t)(k + kk) * D + c0);
                w[kk][0] = wv.x; w[kk][1] = wv.y; w[kk][2] = wv.z; w[kk][3] = wv.w;
            }
            #pragma unroll
            for (int i = 0; i < 4; ++i) {
                float4 av = *reinterpret_cast<const float4*>(&Asf[(rg * 4 + i) * LDS_STRIDE + kb + k]);
                float a[4] = {av.x, av.y, av.z, av.w};
                #pragma unroll
                for (int kk = 0; kk < 4; ++kk)
                    #pragma unroll
                    for (int j = 0; j < 4; ++j)
                        acc[i][j] = fmaf(a[kk], w[kk][j], acc[i][j]);
            }
        }
    }

    float4 bv = *reinterpret_cast<const float4*>(bias + c0);
    float b[4] = {bv.x, bv.y, bv.z, bv.w};
    #pragma unroll
    for (int i = 0; i < 4; ++i) {
        int row = base + rg * 4 + i;
        if (row >= n) continue;
        float o[4];
        #pragma unroll
        for (int j = 0; j < 4; ++j) {
            float v = acc[i][j] + b[j];
            if (do_relu) v = fmaxf(v, 0.f);
            o[j] = v;
        }
        *reinterpret_cast<float4*>(out + (size_t)row * D + c0) =
            make_float4(o[0], o[1], o[2], o[3]);
    }
}

extern "C" void kernel_launch(void* const* d_in, const int* in_sizes, int n_in,
                              void* d_out, int out_size, void* d_ws, size_t ws_size,
                              hipStream_t stream) {
    const float* x       = (const float*)d_in[0];
    const int*   ei      = (const int*)d_in[1];
    const float* W1_rel  = (const float*)d_in[2];
    const float* b1      = (const float*)d_in[3];
    const float* W1_root = (const float*)d_in[4];
    const float* W2_rel  = (const float*)d_in[5];
    const float* b2      = (const float*)d_in[6];
    const float* W2_root = (const float*)d_in[7];
    float* out = (float*)d_out;

    const int E = in_sizes[1] / 2;
    const int N = in_sizes[0] / D;
    const int* src = ei;
    const int* dst = ei + E;

    const int nchunks = (N + SCAN_CHUNK - 1) / SCAN_CHUNK;
    const int eBlocks = (E + 255) / 256;

    // ws layout (bf16 path)
    size_t aggbB = ((size_t)N * D * 2 + 255) & ~(size_t)255;
    size_t xbB   = ((size_t)N * D * 2 + 255) & ~(size_t)255;
    size_t csrB  = ((size_t)E * 4 + 255) & ~(size_t)255;
    size_t ptrB  = ((size_t)(N + 1) * 4 + 255) & ~(size_t)255;
    size_t partB = ((size_t)(nchunks + 1) * 4 + 255) & ~(size_t)255;
    size_t wtB   = (size_t)128 * 256 * 2;           // 64KB each
    size_t need = aggbB + xbB + csrB + ptrB + partB + 2 * wtB;

    if (ws_size >= need) {
        char* w = (char*)d_ws;
        ushort* aggb    = (ushort*)w;            w += aggbB;
        ushort* xb      = (ushort*)w;            w += xbB;    // becomes hb after layer 1
        int*    csr_src = (int*)w;               w += csrB;
        int*    ptr     = (int*)w;               w += ptrB;
        int*    partials= (int*)w;               w += partB;
        ushort* Wt1     = (ushort*)w;            w += wtB;
        ushort* Wt2     = (ushort*)w;

        // CSR build
        hipMemsetAsync(ptr, 0, (size_t)(N + 1) * 4, stream);
        hist_kernel<<<eBlocks, 256, 0, stream>>>(dst, ptr, E);
        scan_reduce_kernel<<<nchunks, 256, 0, stream>>>(ptr, partials, N);
        scan_partials_kernel<<<1, 64, 0, stream>>>(partials, nchunks);
        scan_final_kernel<<<nchunks, 256, 0, stream>>>(ptr, partials, N);
        fill_kernel<<<eBlocks, 256, 0, stream>>>(src, dst, ptr, csr_src, E);
        // ptr now holds ends

        // converts
        int n8 = N * D / 8;
        conv_f32_bf16_kernel<<<(n8 + 255) / 256, 256, 0, stream>>>(x, xb, n8);
        wt_kernel<<<128, 256, 0, stream>>>(W1_rel, W1_root, Wt1);
        wt_kernel<<<128, 256, 0, stream>>>(W2_rel, W2_root, Wt2);

        int gatherBlocks = (N + 15) / 16;
        int gemmBlocks = (N + GBM - 1) / GBM;

        // layer 1: h (bf16) overwrites xb in place (row-disjoint blocks, LDS-staged)
        gather_sum_bf16_kernel<<<gatherBlocks, 256, 0, stream>>>(xb, csr_src, ptr, aggb, N);
        gemm_mfma_kernel<<<gemmBlocks, 256, 0, stream>>>(aggb, xb, Wt1, b1, nullptr, xb, N, 0);
        // layer 2: fp32 out
        gather_sum_bf16_kernel<<<gatherBlocks, 256, 0, stream>>>(xb, csr_src, ptr, aggb, N);
        gemm_mfma_kernel<<<gemmBlocks, 256, 0, stream>>>(aggb, xb, Wt2, b2, out, nullptr, N, 1);
    } else {
        // fallback: fp32 atomic scatter + vector gemm
        float* agg = (float*)d_ws;
        size_t aggBytes = (size_t)N * D * sizeof(float);
        int scatterBlocks = (E * 32 + 255) / 256;
        int gemmBlocks = (N + TILE_R - 1) / TILE_R;
        hipMemsetAsync(agg, 0, aggBytes, stream);
        scatter_add_kernel<<<scatterBlocks, 256, 0, stream>>>(x, src, dst, agg, E);
        gemm_fused_kernel<<<gemmBlocks, 256, 0, stream>>>(agg, x, W1_rel, W1_root, b1, out, N, 1);
        hipMemsetAsync(agg, 0, aggBytes, stream);
        scatter_add_kernel<<<scatterBlocks, 256, 0, stream>>>(out, src, dst, agg, E);
        gemm_fused_kernel<<<gemmBlocks, 256, 0, stream>>>(agg, out, W2_rel, W2_root, b2, out, N, 0);
    }
}

// Round 4
// 290.530 us; speedup vs baseline: 19.3193x; 1.4855x over previous
//
#include <hip/hip_runtime.h>

#define D 128
#define TILE_R 32
#define LDS_STRIDE 260
#define GBM 64            // mfma gemm rows/block
#define APAD 264          // 256 bf16 + 8 pad

#define NB 512            // coarse buckets
#define NPB 256           // nodes per bucket (dst >> 8)
#define EPB_A 2048        // edges per block in stage A

typedef __attribute__((ext_vector_type(8))) short bf16x8;
typedef __attribute__((ext_vector_type(4))) float f32x4;

static __device__ __forceinline__ ushort f2b(float f) {
    union { float f; uint u; } v; v.f = f;
    uint r = (v.u + 0x7FFFu + ((v.u >> 16) & 1u)) >> 16;   // RNE
    return (ushort)r;
}
static __device__ __forceinline__ float blo(uint u) {
    union { uint u; float f; } v; v.u = u << 16; return v.f;
}
static __device__ __forceinline__ float bhi(uint u) {
    union { uint u; float f; } v; v.u = u & 0xFFFF0000u; return v.f;
}

// ================= bucketed CSR build =================

// A1: coarse bucket histogram (LDS-aggregated)
__global__ __launch_bounds__(256) void bucket_count_kernel(
    const int* __restrict__ dst, int* __restrict__ bcnt, int nedges)
{
    __shared__ int h[NB];
    int t = threadIdx.x;
    for (int i = t; i < NB; i += 256) h[i] = 0;
    __syncthreads();
    int base = blockIdx.x * EPB_A;
    #pragma unroll
    for (int i = 0; i < 8; ++i) {
        int e = base + i * 256 + t;
        if (e < nedges) atomicAdd(&h[dst[e] >> 8], 1);
    }
    __syncthreads();
    for (int i = t; i < NB; i += 256) if (h[i]) atomicAdd(&bcnt[i], h[i]);
}

// exclusive scan of 512 bucket counts; writes base + working cursor
__global__ __launch_bounds__(512) void bucket_scan_kernel(
    const int* __restrict__ bcnt, int* __restrict__ bbase, int* __restrict__ bcur)
{
    __shared__ int sh[NB];
    int t = threadIdx.x;
    int v = bcnt[t];
    sh[t] = v; __syncthreads();
    int val = v;
    for (int off = 1; off < NB; off <<= 1) {
        int u = (t >= off) ? sh[t - off] : 0;
        __syncthreads();
        val += u; sh[t] = val; __syncthreads();
    }
    int excl = val - v;
    bbase[t] = excl;
    bcur[t] = excl;
}

// A2: scatter packed entries bucket-contiguously (per-block reservations)
__global__ __launch_bounds__(256) void bucket_scatter_kernel(
    const int* __restrict__ src, const int* __restrict__ dst,
    int* __restrict__ bcur, uint* __restrict__ ebuf, int nedges)
{
    __shared__ int h[NB];
    __shared__ int res[NB];
    int t = threadIdx.x;
    for (int i = t; i < NB; i += 256) h[i] = 0;
    __syncthreads();
    int base = blockIdx.x * EPB_A;
    int d[8], s[8], bkt[8];
    #pragma unroll
    for (int i = 0; i < 8; ++i) {
        int e = base + i * 256 + t;
        if (e < nedges) {
            d[i] = dst[e]; s[i] = src[e]; bkt[i] = d[i] >> 8;
            atomicAdd(&h[bkt[i]], 1);
        } else bkt[i] = -1;
    }
    __syncthreads();
    for (int i = t; i < NB; i += 256) {
        int c = h[i];
        res[i] = c ? atomicAdd(&bcur[i], c) : 0;
    }
    __syncthreads();
    #pragma unroll
    for (int i = 0; i < 8; ++i) {
        if (bkt[i] >= 0) {
            int pos = atomicAdd(&res[bkt[i]], 1);
            ebuf[pos] = ((uint)(d[i] & (NPB - 1)) << 17) | (uint)s[i];
        }
    }
}

// B: one block per bucket -> final CSR (per-node offsets purely local)
__global__ __launch_bounds__(256) void csr_finalize_kernel(
    const uint* __restrict__ ebuf, const int* __restrict__ bbase,
    const int* __restrict__ bcnt, int* __restrict__ csr_src,
    int* __restrict__ ends, int n)
{
    __shared__ int cnt[NPB];
    __shared__ int cur[NPB];
    __shared__ int sh[NPB];
    int b = blockIdx.x, t = threadIdx.x;
    int ebase = bbase[b];
    int ecnt = bcnt[b];
    cnt[t] = 0;
    __syncthreads();
    for (int i = t; i < ecnt; i += 256)
        atomicAdd(&cnt[ebuf[ebase + i] >> 17], 1);
    __syncthreads();
    int v = cnt[t];
    sh[t] = v; __syncthreads();
    int val = v;
    for (int off = 1; off < 256; off <<= 1) {
        int u = (t >= off) ? sh[t - off] : 0;
        __syncthreads();
        val += u; sh[t] = val; __syncthreads();
    }
    int node = b * NPB + t;
    if (node < n) ends[node] = ebase + val;     // inclusive end per node
    cur[t] = ebase + (val - v);                 // start cursor
    __syncthreads();
    for (int i = t; i < ecnt; i += 256) {
        uint p = ebuf[ebase + i];
        int pos = atomicAdd(&cur[p >> 17], 1);
        csr_src[pos] = (int)(p & 0x1FFFFu);
    }
}

// ================= converts =================

__global__ __launch_bounds__(256) void conv_f32_bf16_kernel(
    const float* __restrict__ in, ushort* __restrict__ out, int n8)
{
    int i = blockIdx.x * 256 + threadIdx.x;
    if (i >= n8) return;
    float4 a = reinterpret_cast<const float4*>(in)[i * 2];
    float4 b = reinterpret_cast<const float4*>(in)[i * 2 + 1];
    uint4 r;
    r.x = f2b(a.x) | ((uint)f2b(a.y) << 16);
    r.y = f2b(a.z) | ((uint)f2b(a.w) << 16);
    r.z = f2b(b.x) | ((uint)f2b(b.y) << 16);
    r.w = f2b(b.z) | ((uint)f2b(b.w) << 16);
    reinterpret_cast<uint4*>(out)[i] = r;
}

__global__ __launch_bounds__(256) void wt_kernel(
    const float* __restrict__ Wrel, const float* __restrict__ Wroot,
    ushort* __restrict__ Wt)
{
    int idx = blockIdx.x * 256 + threadIdx.x;   // 128*256 total
    int n = idx >> 8, k = idx & 255;
    float v = (k < 128) ? Wrel[(size_t)k * D + n] : Wroot[(size_t)(k - 128) * D + n];
    Wt[idx] = f2b(v);
}

// ================= gather-sum (bf16 in, bf16 out) =================
__global__ __launch_bounds__(256) void gather_sum_bf16_kernel(
    const ushort* __restrict__ feat, const int* __restrict__ csr_src,
    const int* __restrict__ ends, ushort* __restrict__ aggb, int n)
{
    int node = blockIdx.x * 16 + (threadIdx.x >> 4);
    if (node >= n) return;
    int l = threadIdx.x & 15;
    int start = (node == 0) ? 0 : ends[node - 1];
    int end = ends[node];
    float a0=0,a1=0,a2=0,a3=0,a4=0,a5=0,a6=0,a7=0;
    for (int j = start; j < end; ++j) {
        int s = csr_src[j];
        uint4 v = reinterpret_cast<const uint4*>(feat + (size_t)s * D)[l];
        a0 += blo(v.x); a1 += bhi(v.x);
        a2 += blo(v.y); a3 += bhi(v.y);
        a4 += blo(v.z); a5 += bhi(v.z);
        a6 += blo(v.w); a7 += bhi(v.w);
    }
    uint4 r;
    r.x = f2b(a0) | ((uint)f2b(a1) << 16);
    r.y = f2b(a2) | ((uint)f2b(a3) << 16);
    r.z = f2b(a4) | ((uint)f2b(a5) << 16);
    r.w = f2b(a6) | ((uint)f2b(a7) << 16);
    reinterpret_cast<uint4*>(aggb + (size_t)node * D)[l] = r;
}

// ================= MFMA GEMM =================
__global__ __launch_bounds__(256) void gemm_mfma_kernel(
    const ushort* __restrict__ A1, const ushort* A2,
    const ushort* __restrict__ Wt, const float* __restrict__ bias,
    float* outf, ushort* outb, int n, int mode)
{
    __shared__ ushort As[GBM * APAD];
    const int t = threadIdx.x;
    const int wave = t >> 6, lane = t & 63;
    const int base = blockIdx.x * GBM;

    #pragma unroll
    for (int m = 0; m < 8; ++m) {
        int q = t + m * 256;
        int r = q >> 5;
        int c = q & 31;
        int row = base + r;
        uint4 v = make_uint4(0, 0, 0, 0);
        if (row < n)
            v = (c < 16) ? reinterpret_cast<const uint4*>(A1 + (size_t)row * D)[c]
                         : reinterpret_cast<const uint4*>(A2 + (size_t)row * D)[c - 16];
        *reinterpret_cast<uint4*>(&As[r * APAD + c * 8]) = v;
    }

    const int bcol0 = wave * 32;
    bf16x8 Bfrag[2][8];
    #pragma unroll
    for (int nt = 0; nt < 2; ++nt)
        #pragma unroll
        for (int ks = 0; ks < 8; ++ks) {
            int ncol = bcol0 + nt * 16 + (lane & 15);
            int k = ks * 32 + (lane >> 4) * 8;
            Bfrag[nt][ks] = *reinterpret_cast<const bf16x8*>(Wt + (size_t)ncol * 256 + k);
        }

    __syncthreads();

    f32x4 acc[4][2];
    #pragma unroll
    for (int rt = 0; rt < 4; ++rt)
        #pragma unroll
        for (int nt = 0; nt < 2; ++nt) acc[rt][nt] = (f32x4){0.f, 0.f, 0.f, 0.f};

    #pragma unroll
    for (int ks = 0; ks < 8; ++ks) {
        bf16x8 a[4];
        #pragma unroll
        for (int rt = 0; rt < 4; ++rt) {
            int r = rt * 16 + (lane & 15);
            int k = ks * 32 + (lane >> 4) * 8;
            a[rt] = *reinterpret_cast<const bf16x8*>(&As[r * APAD + k]);
        }
        #pragma unroll
        for (int rt = 0; rt < 4; ++rt)
            #pragma unroll
            for (int nt = 0; nt < 2; ++nt)
                acc[rt][nt] = __builtin_amdgcn_mfma_f32_16x16x32_bf16(
                    a[rt], Bfrag[nt][ks], acc[rt][nt], 0, 0, 0);
    }

    #pragma unroll
    for (int rt = 0; rt < 4; ++rt)
        #pragma unroll
        for (int nt = 0; nt < 2; ++nt) {
            int col = bcol0 + nt * 16 + (lane & 15);
            float bv = bias[col];
            #pragma unroll
            for (int r = 0; r < 4; ++r) {
                int row = base + rt * 16 + (lane >> 4) * 4 + r;
                if (row >= n) continue;
                float v = acc[rt][nt][r] + bv;
                if (mode == 0) {
                    v = fmaxf(v, 0.f);
                    outb[(size_t)row * D + col] = f2b(v);
                } else {
                    outf[(size_t)row * D + col] = v;
                }
            }
        }
}

// ================= fp32 fallback (small ws) =================

__global__ __launch_bounds__(256) void scatter_add_kernel(
    const float* __restrict__ feat, const int* __restrict__ src,
    const int* __restrict__ dst, float* agg, int nedges)
{
    int tid = blockIdx.x * 256 + threadIdx.x;
    int e = tid >> 5;
    if (e >= nedges) return;
    int l = tid & 31;
    int s = src[e];
    int d = dst[e];
    const float4 v = *reinterpret_cast<const float4*>(feat + (size_t)s * D + l * 4);
    float* o = agg + (size_t)d * D + l * 4;
    unsafeAtomicAdd(o + 0, v.x);
    unsafeAtomicAdd(o + 1, v.y);
    unsafeAtomicAdd(o + 2, v.z);
    unsafeAtomicAdd(o + 3, v.w);
}

__global__ __launch_bounds__(256) void gemm_fused_kernel(
    const float* __restrict__ A1, const float* A2,
    const float* __restrict__ Wrel, const float* __restrict__ Wroot,
    const float* __restrict__ bias, float* out, int n, int do_relu)
{
    __shared__ float Asf[TILE_R * LDS_STRIDE];
    const int t = threadIdx.x;
    const int base = blockIdx.x * TILE_R;

    #pragma unroll
    for (int m = 0; m < 8; ++m) {
        int q = t + m * 256;
        int r = q >> 6;
        int kk = (q & 63) << 2;
        int row = base + r;
        float4 v = make_float4(0.f, 0.f, 0.f, 0.f);
        if (row < n) {
            const float* p = (kk < 128) ? (A1 + (size_t)row * D + kk)
                                        : (A2 + (size_t)row * D + (kk - 128));
            v = *reinterpret_cast<const float4*>(p);
        }
        *reinterpret_cast<float4*>(&Asf[r * LDS_STRIDE + kk]) = v;
    }
    __syncthreads();

    const int rg = t >> 5;
    const int c0 = (t & 31) << 2;

    float acc[4][4];
    #pragma unroll
    for (int i = 0; i < 4; ++i)
        #pragma unroll
        for (int j = 0; j < 4; ++j) acc[i][j] = 0.f;

    const float* Wmats[2] = {Wrel, Wroot};
    #pragma unroll
    for (int half = 0; half < 2; ++half) {
        const float* W = Wmats[half];
        const int kb = half * 128;
        for (int k = 0; k < 128; k += 4) {
            float w[4][4];
            #pragma unroll
            for (int kk = 0; kk < 4; ++kk) {
                float4 wv = *reinterpret_cast<const float4*>(W + (size_t)(k + kk) * D + c0);
                w[kk][0] = wv.x; w[kk][1] = wv.y; w[kk][2] = wv.z; w[kk][3] = wv.w;
            }
            #pragma unroll
            for (int i = 0; i < 4; ++i) {
                float4 av = *reinterpret_cast<const float4*>(&Asf[(rg * 4 + i) * LDS_STRIDE + kb + k]);
                float a[4] = {av.x, av.y, av.z, av.w};
                #pragma unroll
                for (int kk = 0; kk < 4; ++kk)
                    #pragma unroll
                    for (int j = 0; j < 4; ++j)
                        acc[i][j] = fmaf(a[kk], w[kk][j], acc[i][j]);
            }
        }
    }

    float4 bv = *reinterpret_cast<const float4*>(bias + c0);
    float b[4] = {bv.x, bv.y, bv.z, bv.w};
    #pragma unroll
    for (int i = 0; i < 4; ++i) {
        int row = base + rg * 4 + i;
        if (row >= n) continue;
        float o[4];
        #pragma unroll
        for (int j = 0; j < 4; ++j) {
            float v = acc[i][j] + b[j];
            if (do_relu) v = fmaxf(v, 0.f);
            o[j] = v;
        }
        *reinterpret_cast<float4*>(out + (size_t)row * D + c0) =
            make_float4(o[0], o[1], o[2], o[3]);
    }
}

extern "C" void kernel_launch(void* const* d_in, const int* in_sizes, int n_in,
                              void* d_out, int out_size, void* d_ws, size_t ws_size,
                              hipStream_t stream) {
    const float* x       = (const float*)d_in[0];
    const int*   ei      = (const int*)d_in[1];
    const float* W1_rel  = (const float*)d_in[2];
    const float* b1      = (const float*)d_in[3];
    const float* W1_root = (const float*)d_in[4];
    const float* W2_rel  = (const float*)d_in[5];
    const float* b2      = (const float*)d_in[6];
    const float* W2_root = (const float*)d_in[7];
    float* out = (float*)d_out;

    const int E = in_sizes[1] / 2;
    const int N = in_sizes[0] / D;
    const int* src = ei;
    const int* dst = ei + E;

    // ws layout (bf16 bucketed path). ebuf aliases aggb (dead before gathers).
    size_t aggbB = ((size_t)N * D * 2 + 255) & ~(size_t)255;       // >= E*4 needed too
    size_t xbB   = ((size_t)N * D * 2 + 255) & ~(size_t)255;
    size_t csrB  = ((size_t)E * 4 + 255) & ~(size_t)255;
    size_t endB  = ((size_t)(N + 1) * 4 + 255) & ~(size_t)255;
    size_t bktB  = ((size_t)(3 * NB + 8) * 4 + 255) & ~(size_t)255;
    size_t wtB   = (size_t)128 * 256 * 2;
    size_t need = aggbB + xbB + csrB + endB + bktB + 2 * wtB;

    bool pack_ok = (N <= 131072) && ((size_t)E * 4 <= aggbB);

    if (ws_size >= need && pack_ok) {
        char* w = (char*)d_ws;
        ushort* aggb    = (ushort*)w;            w += aggbB;
        ushort* xb      = (ushort*)w;            w += xbB;
        int*    csr_src = (int*)w;               w += csrB;
        int*    ends    = (int*)w;               w += endB;
        int*    bcnt    = (int*)w;
        int*    bbase   = bcnt + NB;
        int*    bcur    = bbase + NB;            w += bktB;
        ushort* Wt1     = (ushort*)w;            w += wtB;
        ushort* Wt2     = (ushort*)w;
        uint*   ebuf    = (uint*)aggb;           // alias: dead before gathers

        const int aBlocks = (E + EPB_A - 1) / EPB_A;
        const int nbu = (N + NPB - 1) / NPB;

        // bucketed CSR build
        hipMemsetAsync(bcnt, 0, NB * sizeof(int), stream);
        bucket_count_kernel<<<aBlocks, 256, 0, stream>>>(dst, bcnt, E);
        bucket_scan_kernel<<<1, NB, 0, stream>>>(bcnt, bbase, bcur);
        bucket_scatter_kernel<<<aBlocks, 256, 0, stream>>>(src, dst, bcur, ebuf, E);
        csr_finalize_kernel<<<nbu, 256, 0, stream>>>(ebuf, bbase, bcnt, csr_src, ends, N);

        // converts
        int n8 = N * D / 8;
        conv_f32_bf16_kernel<<<(n8 + 255) / 256, 256, 0, stream>>>(x, xb, n8);
        wt_kernel<<<128, 256, 0, stream>>>(W1_rel, W1_root, Wt1);
        wt_kernel<<<128, 256, 0, stream>>>(W2_rel, W2_root, Wt2);

        int gatherBlocks = (N + 15) / 16;
        int gemmBlocks = (N + GBM - 1) / GBM;

        // layer 1 (h bf16 overwrites xb in place; row-disjoint, LDS-staged)
        gather_sum_bf16_kernel<<<gatherBlocks, 256, 0, stream>>>(xb, csr_src, ends, aggb, N);
        gemm_mfma_kernel<<<gemmBlocks, 256, 0, stream>>>(aggb, xb, Wt1, b1, nullptr, xb, N, 0);
        // layer 2 (fp32 out)
        gather_sum_bf16_kernel<<<gatherBlocks, 256, 0, stream>>>(xb, csr_src, ends, aggb, N);
        gemm_mfma_kernel<<<gemmBlocks, 256, 0, stream>>>(aggb, xb, Wt2, b2, out, nullptr, N, 1);
    } else {
        // fallback: fp32 atomic scatter + vector gemm
        float* agg = (float*)d_ws;
        size_t aggBytes = (size_t)N * D * sizeof(float);
        int scatterBlocks = (E * 32 + 255) / 256;
        int gemmBlocks = (N + TILE_R - 1) / TILE_R;
        hipMemsetAsync(agg, 0, aggBytes, stream);
        scatter_add_kernel<<<scatterBlocks, 256, 0, stream>>>(x, src, dst, agg, E);
        gemm_fused_kernel<<<gemmBlocks, 256, 0, stream>>>(agg, x, W1_rel, W1_root, b1, out, N, 1);
        hipMemsetAsync(agg, 0, aggBytes, stream);
        scatter_add_kernel<<<scatterBlocks, 256, 0, stream>>>(out, src, dst, agg, E);
        gemm_fused_kernel<<<gemmBlocks, 256, 0, stream>>>(agg, out, W2_rel, W2_root, b2, out, N, 0);
    }
}